// Round 16
// baseline (41.044 us; speedup 1.0000x reference)
//
#include <hip/hip_runtime.h>
#include <math.h>

// UnrolledMeanShift: B=2, D=32, H=W=256, K=5x5, 3 iterations.
// R16 = R10's register-cache design, UN-STRANGLED: R10 ran with
// launch_bounds(512,4)=64-VGPR cap vs a ~115-reg live set -> hidden spill
// (same failure as R12; top-5 was fillBuffer so it was never visible).
// Now: 4 threads/pixel (8ch each, DPP-quad reduce), 25 INDIVIDUALLY-NAMED
// u4v window cache (~100 VGPR) filled from LDS once -> ZERO in-loop DS.
// launch_bounds(512,2): VGPR budget 256, compiler lands ~118-128 -> 16 w/CU.
// Scaled space: staged values pre-multiplied by s=sqrt(NC*log2e) so
// |p_s - z_s|^2 IS the exp2 argument (negation folds into v_exp modifier).
// Final write: out = num_s * invf / s. R15's vectorized staging (float4 x8 +
// register transpose) with the pre-scale folded into the cvt.

typedef _Float16 h2  __attribute__((ext_vector_type(2)));
typedef unsigned int u4v __attribute__((ext_vector_type(4)));

constexpr int Dch  = 32;
constexpr int HH   = 256;
constexpr int WW   = 256;
constexpr int BH   = 8;               // tile rows
constexpr int BW   = 16;              // tile cols
constexpr int THs  = 12;              // staged rows (rel -2..9)
constexpr int RSTR = 25;              // staged row stride: 24 cols + 1 pad
constexpr int PSTR = THs * RSTR + 1;  // 301 words plane stride
constexpr int NJOB = 4 * THs * 6;     // 288 staging jobs
constexpr int ITERS = 3;
constexpr int HWp  = HH * WW;
constexpr int NTHR = 512;             // 128 pixels x 4 ch-quarter threads

__device__ __forceinline__ float fdot2f(h2 a, h2 b, float c) {
    return __builtin_amdgcn_fdot2(a, b, c, false);
}

__device__ __forceinline__ float EXP2F(float x) {
#if __has_builtin(__builtin_amdgcn_exp2f)
    return __builtin_amdgcn_exp2f(x);
#else
    return __expf(x * 0.69314718055994531f);
#endif
}

// lane^1 within quad (quad_perm [1,0,3,2])
__device__ __forceinline__ float qswap1(float x) {
    return __int_as_float(
        __builtin_amdgcn_mov_dpp(__float_as_int(x), 0xB1, 0xF, 0xF, true));
}
// lane^2 within quad (quad_perm [2,3,0,1])
__device__ __forceinline__ float qswap2(float x) {
    return __int_as_float(
        __builtin_amdgcn_mov_dpp(__float_as_int(x), 0x4E, 0xF, 0xF, true));
}

__device__ __forceinline__ h2 as_h2(unsigned int x) {
    return __builtin_bit_cast(h2, x);
}

__device__ __forceinline__ h2 pk2(float a, float b) {
#if __has_builtin(__builtin_amdgcn_cvt_pkrtz)
    return __builtin_bit_cast(h2, __builtin_amdgcn_cvt_pkrtz(a, b));
#else
    h2 r; r[0] = (_Float16)a; r[1] = (_Float16)b; return r;
#endif
}

__device__ __forceinline__ unsigned int pku(float a, float b) {
    return __builtin_bit_cast(unsigned int, pk2(a, b));
}

__global__ __launch_bounds__(NTHR, 2)
void meanshift_kernel(const float* __restrict__ E,
                      const float* __restrict__ lbw,
                      float* __restrict__ out)
{
    __shared__ u4v tile[4 * PSTR];       // 19.3 KB (fp16 scaled, 8ch/16B)

    const int bz  = blockIdx.z;
    const int oh  = blockIdx.y * BH - 2;       // staged row 0 = rel -2
    const int owc = blockIdx.x * BW;           // true tile col origin
    const int gw0 = owc - 4;                   // staged col 0 = rel -4
    const int tid = threadIdx.x;
    const int cq  = tid & 3;                   // channel quarter (DPP quad)
    const int idx = tid >> 2;                  // 0..127 pixel in tile
    const int px  = idx & (BW - 1);
    const int py  = idx >> 4;

    const float bwv = log1pf(__expf(lbw[0]));      // softplus
    const float cc2 = 1.0f / (2.0f * bwv * bwv);
    const float NCf = cc2 * 1.44269504f;           // w = 2^(-NC*dist^2)
    const float scl = __builtin_sqrtf(NCf);        // work in scaled space
    const float isc = 1.0f / scl;

    const float* Eb = E + (size_t)bz * Dch * HWp;

    // ---- vectorized staging (R15), pre-scaled by scl ----
    if (tid < NJOB) {
        const int cc  = tid / (THs * 6);
        const int rem = tid - cc * (THs * 6);
        const int row = rem / 6;
        const int g   = rem - row * 6;
        const int gh  = oh + row;
        const int gwb = gw0 + 4 * g;

        float4 F0 = {0.f,0.f,0.f,0.f}, F1 = F0, F2 = F0, F3 = F0;
        float4 F4 = F0, F5 = F0, F6 = F0, F7 = F0;
        if ((unsigned)gh < (unsigned)HH) {
            const float* base = Eb + (size_t)(8 * cc) * HWp + gh * WW;
            if (gwb >= 0 && gwb + 4 <= WW) {       // aligned fast path
                F0 = *(const float4*)(base + 0 * (size_t)HWp + gwb);
                F1 = *(const float4*)(base + 1 * (size_t)HWp + gwb);
                F2 = *(const float4*)(base + 2 * (size_t)HWp + gwb);
                F3 = *(const float4*)(base + 3 * (size_t)HWp + gwb);
                F4 = *(const float4*)(base + 4 * (size_t)HWp + gwb);
                F5 = *(const float4*)(base + 5 * (size_t)HWp + gwb);
                F6 = *(const float4*)(base + 6 * (size_t)HWp + gwb);
                F7 = *(const float4*)(base + 7 * (size_t)HWp + gwb);
            } else {                                // edge: per-element
                const bool i0 = (unsigned)(gwb + 0) < (unsigned)WW;
                const bool i1 = (unsigned)(gwb + 1) < (unsigned)WW;
                const bool i2 = (unsigned)(gwb + 2) < (unsigned)WW;
                const bool i3 = (unsigned)(gwb + 3) < (unsigned)WW;
#define GE(K) F##K = make_float4( \
                    i0 ? base[(K) * (size_t)HWp + gwb + 0] : 0.f, \
                    i1 ? base[(K) * (size_t)HWp + gwb + 1] : 0.f, \
                    i2 ? base[(K) * (size_t)HWp + gwb + 2] : 0.f, \
                    i3 ? base[(K) * (size_t)HWp + gwb + 3] : 0.f)
                GE(0); GE(1); GE(2); GE(3); GE(4); GE(5); GE(6); GE(7);
#undef GE
            }
        }
        const int wbase = cc * PSTR + row * RSTR + 4 * g;
        u4v W;
        W[0]=pku(F0.x*scl,F1.x*scl); W[1]=pku(F2.x*scl,F3.x*scl);
        W[2]=pku(F4.x*scl,F5.x*scl); W[3]=pku(F6.x*scl,F7.x*scl);
        tile[wbase + 0] = W;
        W[0]=pku(F0.y*scl,F1.y*scl); W[1]=pku(F2.y*scl,F3.y*scl);
        W[2]=pku(F4.y*scl,F5.y*scl); W[3]=pku(F6.y*scl,F7.y*scl);
        tile[wbase + 1] = W;
        W[0]=pku(F0.z*scl,F1.z*scl); W[1]=pku(F2.z*scl,F3.z*scl);
        W[2]=pku(F4.z*scl,F5.z*scl); W[3]=pku(F6.z*scl,F7.z*scl);
        tile[wbase + 2] = W;
        W[0]=pku(F0.w*scl,F1.w*scl); W[1]=pku(F2.w*scl,F3.w*scl);
        W[2]=pku(F4.w*scl,F5.w*scl); W[3]=pku(F6.w*scl,F7.w*scl);
        tile[wbase + 3] = W;
    }
    __syncthreads();

    const u4v* __restrict__ tP = tile + cq * PSTR;   // my 8-channel plane

    // ---- register-cache the 5x5 window: 25 NAMED u4v (~100 VGPR) ----
    const int rb0 = (py + 0) * RSTR + (px + 2);
    const int rb1 = rb0 + RSTR;
    const int rb2 = rb1 + RSTR;
    const int rb3 = rb2 + RSTR;
    const int rb4 = rb3 + RSTR;
    const u4v c00 = tP[rb0+0], c01 = tP[rb0+1], c02 = tP[rb0+2], c03 = tP[rb0+3], c04 = tP[rb0+4];
    const u4v c10 = tP[rb1+0], c11 = tP[rb1+1], c12 = tP[rb1+2], c13 = tP[rb1+3], c14 = tP[rb1+4];
    const u4v c20 = tP[rb2+0], c21 = tP[rb2+1], c22 = tP[rb2+2], c23 = tP[rb2+3], c24 = tP[rb2+4];
    const u4v c30 = tP[rb3+0], c31 = tP[rb3+1], c32 = tP[rb3+2], c33 = tP[rb3+3], c34 = tP[rb3+4];
    const u4v c40 = tP[rb4+0], c41 = tP[rb4+1], c42 = tP[rb4+2], c43 = tP[rb4+3], c44 = tP[rb4+4];

    // ---- init z (scaled) = own pixel (center c22), my 8 channels ----
    h2 z0 = as_h2(c22[0]), z1 = as_h2(c22[1]);
    h2 z2 = as_h2(c22[2]), z3 = as_h2(c22[3]);

    float* Ob = out + (size_t)bz * Dch * HWp;
    const int off    = (oh + 2 + py) * WW + (owc + px);
    const int chbase = 8 * cq;

#define NBODY(Q) do {                                                         \
        const h2 p0 = as_h2(Q[0]), p1 = as_h2(Q[1]);                          \
        const h2 p2 = as_h2(Q[2]), p3 = as_h2(Q[3]);                          \
        const h2 e0 = p0 - z0, e1 = p1 - z1;                                  \
        const h2 e2 = p2 - z2, e3 = p3 - z3;                                  \
        float s0 = fdot2f(e0, e0, 0.f);                                       \
        float s1 = fdot2f(e1, e1, 0.f);                                       \
        s0 = fdot2f(e2, e2, s0);                                              \
        s1 = fdot2f(e3, e3, s1);                                              \
        const float dp = s0 + s1;             /* my 8 ch (scaled) */          \
        const float d2 = dp + qswap1(dp);                                     \
        const float d4 = d2 + qswap2(d2);     /* full 32 ch */                \
        const float w  = EXP2F(-d4);          /* neg folds into v_exp */      \
        den += w;                                                             \
        const h2 w2v = pk2(w, w);                                             \
        n0 += p0 * w2v; n1 += p1 * w2v;                                       \
        n2 += p2 * w2v; n3 += p3 * w2v;                                       \
    } while (0)

    #pragma unroll 1
    for (int it = 0; it < ITERS; ++it) {
        h2 n0 = {(_Float16)0.f, (_Float16)0.f};
        h2 n1 = n0, n2 = n0, n3 = n0;
        float den = 0.f;

        NBODY(c00); NBODY(c01); NBODY(c02); NBODY(c03); NBODY(c04);
        NBODY(c10); NBODY(c11); NBODY(c12); NBODY(c13); NBODY(c14);
        NBODY(c20); NBODY(c21); NBODY(c22); NBODY(c23); NBODY(c24);
        NBODY(c30); NBODY(c31); NBODY(c32); NBODY(c33); NBODY(c34);
        NBODY(c40); NBODY(c41); NBODY(c42); NBODY(c43); NBODY(c44);

        const float invf = 1.0f / (den + 1e-6f);
        if (it == ITERS - 1) {
            const float fin = invf * isc;     // unscale on the way out
#define WR(IDX, NV, EL) Ob[(size_t)(chbase + (IDX)) * HWp + off] = (float)NV[EL] * fin
            WR(0, n0, 0); WR(1, n0, 1); WR(2, n1, 0); WR(3, n1, 1);
            WR(4, n2, 0); WR(5, n2, 1); WR(6, n3, 0); WR(7, n3, 1);
#undef WR
        } else {
            const h2 iv = pk2(invf, invf);    // stays in scaled space
            z0 = n0 * iv; z1 = n1 * iv; z2 = n2 * iv; z3 = n3 * iv;
        }
    }
#undef NBODY
}

extern "C" void kernel_launch(void* const* d_in, const int* in_sizes, int n_in,
                              void* d_out, int out_size, void* d_ws, size_t ws_size,
                              hipStream_t stream) {
    const float* E   = (const float*)d_in[0];
    const float* lbw = (const float*)d_in[1];
    float* out       = (float*)d_out;

    const int B = in_sizes[0] / (Dch * HWp);       // = 2
    dim3 grid(WW / BW, HH / BH, B);                // (16,32,2) = 1024 blocks
    dim3 block(NTHR, 1, 1);                        // 512 threads (4/pixel)
    hipLaunchKernelGGL(meanshift_kernel, grid, block, 0, stream, E, lbw, out);
}

// Round 17
// 34.591 us; speedup vs baseline: 1.1866x; 1.1866x over previous
//
#include <hip/hip_runtime.h>
#include <math.h>

// UnrolledMeanShift: B=2, D=32, H=W=256, K=5x5, 3 iterations.
// R17 = R14 math (dot-expansion: arg = A2 p.z - NC|p|^2 - NC|z|^2, S from
// LDS, packed-fp16 num, 2 ch-halves + DPP pair-combine) + VERTICAL-PAIR
// sharing (R8's -40% DS idea, redone at 16 waves/CU): 16x32 tile, 512 thr =
// 2 halves x 256 vertical pixel-pairs; per di-group the 5+5 tile words and
// 5 S values are read ONCE and feed both pixels' NBODYs.
// Rationale: per-CU DS-pipe accounting matches measured per-iter cost
// (R15 loop: 25x(2x12+5.8)x16waves = 11.9k cyc/CU/iter ~ 5us) -> loop is
// DS-issue-bound; this cuts wave-level DS ~45%.

typedef _Float16 h2  __attribute__((ext_vector_type(2)));
typedef unsigned int u4v __attribute__((ext_vector_type(4)));

constexpr int Dch  = 32;
constexpr int HH   = 256;
constexpr int WW   = 256;
constexpr int BH   = 32;              // tile rows
constexpr int BW   = 16;              // tile cols
constexpr int THs  = 36;              // staged rows (rel -2..33)
constexpr int RSTR = 25;              // staged row stride (24 cols + pad)
constexpr int PSTR = THs * RSTR + 1;  // 901 words plane stride
constexpr int NJOB = 4 * THs * 6;     // 864 staging jobs
constexpr int ITERS = 3;
constexpr int HWp  = HH * WW;
constexpr int NTHR = 512;

__device__ __forceinline__ float fdot2f(h2 a, h2 b, float c) {
    return __builtin_amdgcn_fdot2(a, b, c, false);
}

__device__ __forceinline__ float EXP2F(float x) {
#if __has_builtin(__builtin_amdgcn_exp2f)
    return __builtin_amdgcn_exp2f(x);
#else
    return __expf(x * 0.69314718055994531f);
#endif
}

// value from lane^1 (quad_perm [1,0,3,2]) — pure VALU, no LDS pipe
__device__ __forceinline__ float qswap(float x) {
#if __has_builtin(__builtin_amdgcn_mov_dpp)
    return __int_as_float(
        __builtin_amdgcn_mov_dpp(__float_as_int(x), 0xB1, 0xF, 0xF, true));
#else
    return __shfl_xor(x, 1, 64);
#endif
}

__device__ __forceinline__ h2 as_h2(unsigned int x) {
    return __builtin_bit_cast(h2, x);
}

__device__ __forceinline__ h2 pk2(float a, float b) {
#if __has_builtin(__builtin_amdgcn_cvt_pkrtz)
    return __builtin_bit_cast(h2, __builtin_amdgcn_cvt_pkrtz(a, b));
#else
    h2 r; r[0] = (_Float16)a; r[1] = (_Float16)b; return r;
#endif
}

__device__ __forceinline__ unsigned int pku(float a, float b) {
    return __builtin_bit_cast(unsigned int, pk2(a, b));
}

__global__ __launch_bounds__(NTHR, 2)
void meanshift_kernel(const float* __restrict__ E,
                      const float* __restrict__ lbw,
                      float* __restrict__ out)
{
    __shared__ u4v  tile[4 * PSTR];      // 57.7 KB (fp16, 8ch/16B word)
    __shared__ float sqv[THs * RSTR];    // -0.5*NC*|p|^2 (full 32 ch)

    const int bz  = blockIdx.z;
    const int oh  = blockIdx.y * BH - 2;       // staged row 0 = rel -2
    const int owc = blockIdx.x * BW;
    const int gw0 = owc - 4;                   // staged col 0 = rel -4
    const int tid = threadIdx.x;
    const int half = tid & 1;                  // channel half
    const int pr   = tid >> 1;                 // 0..255 pixel-pair
    const int px   = pr & (BW - 1);
    const int pyy  = pr >> 4;                  // 0..15
    const int py0  = 2 * pyy;                  // upper pixel row (A)
    const int c0   = 2 * half;

    const float bwv = log1pf(__expf(lbw[0]));     // softplus
    const float cc2 = 1.0f / (2.0f * bwv * bwv);
    const float NCf = cc2 * 1.44269504f;          // w = 2^(-NC*dist^2)
    const float A2f = 2.0f * NCf;
    const float MZC = -1.0f / (8.0f * NCf);       // mzz = MZC * |zs|^2_full

    const float* Eb = E + (size_t)bz * Dch * HWp;

    // ---- vectorized staging (R15): 8 x float4 + register transpose ----
    for (int job = tid; job < NJOB; job += NTHR) {
        const int cc  = job / (THs * 6);
        const int rem = job - cc * (THs * 6);
        const int row = rem / 6;
        const int g   = rem - row * 6;
        const int gh  = oh + row;
        const int gwb = gw0 + 4 * g;

        float4 F0 = {0.f,0.f,0.f,0.f}, F1 = F0, F2 = F0, F3 = F0;
        float4 F4 = F0, F5 = F0, F6 = F0, F7 = F0;
        if ((unsigned)gh < (unsigned)HH) {
            const float* base = Eb + (size_t)(8 * cc) * HWp + gh * WW;
            if (gwb >= 0 && gwb + 4 <= WW) {
                F0 = *(const float4*)(base + 0 * (size_t)HWp + gwb);
                F1 = *(const float4*)(base + 1 * (size_t)HWp + gwb);
                F2 = *(const float4*)(base + 2 * (size_t)HWp + gwb);
                F3 = *(const float4*)(base + 3 * (size_t)HWp + gwb);
                F4 = *(const float4*)(base + 4 * (size_t)HWp + gwb);
                F5 = *(const float4*)(base + 5 * (size_t)HWp + gwb);
                F6 = *(const float4*)(base + 6 * (size_t)HWp + gwb);
                F7 = *(const float4*)(base + 7 * (size_t)HWp + gwb);
            } else {
                const bool i0 = (unsigned)(gwb + 0) < (unsigned)WW;
                const bool i1 = (unsigned)(gwb + 1) < (unsigned)WW;
                const bool i2 = (unsigned)(gwb + 2) < (unsigned)WW;
                const bool i3 = (unsigned)(gwb + 3) < (unsigned)WW;
#define GE(K) F##K = make_float4( \
                    i0 ? base[(K) * (size_t)HWp + gwb + 0] : 0.f, \
                    i1 ? base[(K) * (size_t)HWp + gwb + 1] : 0.f, \
                    i2 ? base[(K) * (size_t)HWp + gwb + 2] : 0.f, \
                    i3 ? base[(K) * (size_t)HWp + gwb + 3] : 0.f)
                GE(0); GE(1); GE(2); GE(3); GE(4); GE(5); GE(6); GE(7);
#undef GE
            }
        }
        const int wbase = cc * PSTR + row * RSTR + 4 * g;
        u4v W;
        W[0]=pku(F0.x,F1.x); W[1]=pku(F2.x,F3.x); W[2]=pku(F4.x,F5.x); W[3]=pku(F6.x,F7.x);
        tile[wbase + 0] = W;
        W[0]=pku(F0.y,F1.y); W[1]=pku(F2.y,F3.y); W[2]=pku(F4.y,F5.y); W[3]=pku(F6.y,F7.y);
        tile[wbase + 1] = W;
        W[0]=pku(F0.z,F1.z); W[1]=pku(F2.z,F3.z); W[2]=pku(F4.z,F5.z); W[3]=pku(F6.z,F7.z);
        tile[wbase + 2] = W;
        W[0]=pku(F0.w,F1.w); W[1]=pku(F2.w,F3.w); W[2]=pku(F4.w,F5.w); W[3]=pku(F6.w,F7.w);
        tile[wbase + 3] = W;
    }
    __syncthreads();

    // ---- precompute sqv = -0.5*NC*|p|^2 (all 32 ch), strided ----
    for (int q = tid; q < THs * 24; q += NTHR) {
        const int row = q / 24;
        const int col = q - row * 24;
        const int p   = row * RSTR + col;
        const u4v t0 = tile[0 * PSTR + p], t1 = tile[1 * PSTR + p];
        const u4v t2 = tile[2 * PSTR + p], t3 = tile[3 * PSTR + p];
        float a0 = 0.f, a1 = 0.f, a2 = 0.f, a3 = 0.f;
        #pragma unroll
        for (int j = 0; j < 4; ++j) {
            const h2 q0 = as_h2(t0[j]); a0 = fdot2f(q0, q0, a0);
            const h2 q1 = as_h2(t1[j]); a1 = fdot2f(q1, q1, a1);
            const h2 q2 = as_h2(t2[j]); a2 = fdot2f(q2, q2, a2);
            const h2 q3 = as_h2(t3[j]); a3 = fdot2f(q3, q3, a3);
        }
        sqv[p] = -0.5f * NCf * ((a0 + a1) + (a2 + a3));
    }
    __syncthreads();

    const u4v* __restrict__ tA = tile + c0 * PSTR;
    const u4v* __restrict__ tB = tA + PSTR;

    // ---- init zs = A2*z for both pixels of the pair ----
    h2 zA0, zA1, zA2, zA3, zA4, zA5, zA6, zA7;
    h2 zB0, zB1, zB2, zB3, zB4, zB5, zB6, zB7;
    {
        const int mypA = (py0 + 2) * RSTR + (px + 4);
        const int mypB = mypA + RSTR;
        const h2 A2v = pk2(A2f, A2f);
        const u4v ca = tA[mypA], cb = tB[mypA];
        zA0 = as_h2(ca[0]) * A2v; zA1 = as_h2(ca[1]) * A2v;
        zA2 = as_h2(ca[2]) * A2v; zA3 = as_h2(ca[3]) * A2v;
        zA4 = as_h2(cb[0]) * A2v; zA5 = as_h2(cb[1]) * A2v;
        zA6 = as_h2(cb[2]) * A2v; zA7 = as_h2(cb[3]) * A2v;
        const u4v da = tA[mypB], db = tB[mypB];
        zB0 = as_h2(da[0]) * A2v; zB1 = as_h2(da[1]) * A2v;
        zB2 = as_h2(da[2]) * A2v; zB3 = as_h2(da[3]) * A2v;
        zB4 = as_h2(db[0]) * A2v; zB5 = as_h2(db[1]) * A2v;
        zB6 = as_h2(db[2]) * A2v; zB7 = as_h2(db[3]) * A2v;
    }

    float* Ob = out + (size_t)bz * Dch * HWp;
    const int offA   = (oh + 2 + py0) * WW + (owc + px);
    const int chbase = 16 * half;

// compute one neighbor for one pixel from preloaded words
#define NB(PA0,PA1,PA2,PA3,PB0,PB1,PB2,PB3, SV, ZP, NP, DEN, MZZ) do {        \
        float s0 = fdot2f(PA0, ZP##0, (SV));                                  \
        s0 = fdot2f(PA1, ZP##1, s0); s0 = fdot2f(PA2, ZP##2, s0);             \
        s0 = fdot2f(PA3, ZP##3, s0);                                          \
        float s1 = fdot2f(PB0, ZP##4, (MZZ));                                 \
        s1 = fdot2f(PB1, ZP##5, s1); s1 = fdot2f(PB2, ZP##6, s1);             \
        s1 = fdot2f(PB3, ZP##7, s1);                                          \
        const float dp  = s0 + s1;                                            \
        const float arg = dp + qswap(dp);                                     \
        const float w   = EXP2F(arg);                                         \
        DEN += w;                                                             \
        const h2 w2v = pk2(w, w);                                             \
        NP##0 += PA0 * w2v; NP##1 += PA1 * w2v;                               \
        NP##2 += PA2 * w2v; NP##3 += PA3 * w2v;                               \
        NP##4 += PB0 * w2v; NP##5 += PB1 * w2v;                               \
        NP##6 += PB2 * w2v; NP##7 += PB3 * w2v;                               \
    } while (0)

    #pragma unroll 1
    for (int it = 0; it < ITERS; ++it) {
        // mzz for both pixels: -0.5*NC*|z|^2 from |zs|^2 = A2^2 |z|^2
        float mzzA, mzzB;
        {
            float q0 = fdot2f(zA0, zA0, 0.f);
            q0 = fdot2f(zA1, zA1, q0); q0 = fdot2f(zA2, zA2, q0);
            q0 = fdot2f(zA3, zA3, q0);
            float q1 = fdot2f(zA4, zA4, 0.f);
            q1 = fdot2f(zA5, zA5, q1); q1 = fdot2f(zA6, zA6, q1);
            q1 = fdot2f(zA7, zA7, q1);
            const float qa = q0 + q1;
            mzzA = (qa + qswap(qa)) * MZC;
            float r0 = fdot2f(zB0, zB0, 0.f);
            r0 = fdot2f(zB1, zB1, r0); r0 = fdot2f(zB2, zB2, r0);
            r0 = fdot2f(zB3, zB3, r0);
            float r1 = fdot2f(zB4, zB4, 0.f);
            r1 = fdot2f(zB5, zB5, r1); r1 = fdot2f(zB6, zB6, r1);
            r1 = fdot2f(zB7, zB7, r1);
            const float qb = r0 + r1;
            mzzB = (qb + qswap(qb)) * MZC;
        }

        h2 nA0 = {(_Float16)0.f, (_Float16)0.f};
        h2 nA1 = nA0, nA2 = nA0, nA3 = nA0, nA4 = nA0, nA5 = nA0, nA6 = nA0, nA7 = nA0;
        h2 nB0 = nA0, nB1 = nA0, nB2 = nA0, nB3 = nA0, nB4 = nA0, nB5 = nA0, nB6 = nA0, nB7 = nA0;
        float denA = 0.f, denB = 0.f;

        #pragma unroll 1
        for (int di = 0; di < 6; ++di) {
            const int rw = (py0 + di) * RSTR + (px + 2);
            // shared reads: 5 cols x 2 planes + 5 S values (once per pair)
            const u4v qa0 = tA[rw+0], qa1 = tA[rw+1], qa2 = tA[rw+2];
            const u4v qa3 = tA[rw+3], qa4 = tA[rw+4];
            const u4v qb0 = tB[rw+0], qb1 = tB[rw+1], qb2 = tB[rw+2];
            const u4v qb3 = tB[rw+3], qb4 = tB[rw+4];
            const float S0 = sqv[rw+0], S1 = sqv[rw+1], S2 = sqv[rw+2];
            const float S3 = sqv[rw+3], S4 = sqv[rw+4];
#define EXPAND(Q) as_h2(Q[0]), as_h2(Q[1]), as_h2(Q[2]), as_h2(Q[3])
            const h2 a00 = as_h2(qa0[0]), a01 = as_h2(qa0[1]), a02 = as_h2(qa0[2]), a03 = as_h2(qa0[3]);
            const h2 a10 = as_h2(qa1[0]), a11 = as_h2(qa1[1]), a12 = as_h2(qa1[2]), a13 = as_h2(qa1[3]);
            const h2 a20 = as_h2(qa2[0]), a21 = as_h2(qa2[1]), a22 = as_h2(qa2[2]), a23 = as_h2(qa2[3]);
            const h2 a30 = as_h2(qa3[0]), a31 = as_h2(qa3[1]), a32 = as_h2(qa3[2]), a33 = as_h2(qa3[3]);
            const h2 a40 = as_h2(qa4[0]), a41 = as_h2(qa4[1]), a42 = as_h2(qa4[2]), a43 = as_h2(qa4[3]);
            const h2 b00 = as_h2(qb0[0]), b01 = as_h2(qb0[1]), b02 = as_h2(qb0[2]), b03 = as_h2(qb0[3]);
            const h2 b10 = as_h2(qb1[0]), b11 = as_h2(qb1[1]), b12 = as_h2(qb1[2]), b13 = as_h2(qb1[3]);
            const h2 b20 = as_h2(qb2[0]), b21 = as_h2(qb2[1]), b22 = as_h2(qb2[2]), b23 = as_h2(qb2[3]);
            const h2 b30 = as_h2(qb3[0]), b31 = as_h2(qb3[1]), b32 = as_h2(qb3[2]), b33 = as_h2(qb3[3]);
            const h2 b40 = as_h2(qb4[0]), b41 = as_h2(qb4[1]), b42 = as_h2(qb4[2]), b43 = as_h2(qb4[3]);
#undef EXPAND
            if (di != 5) {   // rows 0..4 feed pixel A
                NB(a00,a01,a02,a03, b00,b01,b02,b03, S0, zA, nA, denA, mzzA);
                NB(a10,a11,a12,a13, b10,b11,b12,b13, S1, zA, nA, denA, mzzA);
                NB(a20,a21,a22,a23, b20,b21,b22,b23, S2, zA, nA, denA, mzzA);
                NB(a30,a31,a32,a33, b30,b31,b32,b33, S3, zA, nA, denA, mzzA);
                NB(a40,a41,a42,a43, b40,b41,b42,b43, S4, zA, nA, denA, mzzA);
            }
            if (di != 0) {   // rows 1..5 feed pixel B
                NB(a00,a01,a02,a03, b00,b01,b02,b03, S0, zB, nB, denB, mzzB);
                NB(a10,a11,a12,a13, b10,b11,b12,b13, S1, zB, nB, denB, mzzB);
                NB(a20,a21,a22,a23, b20,b21,b22,b23, S2, zB, nB, denB, mzzB);
                NB(a30,a31,a32,a33, b30,b31,b32,b33, S3, zB, nB, denB, mzzB);
                NB(a40,a41,a42,a43, b40,b41,b42,b43, S4, zB, nB, denB, mzzB);
            }
        }

        const float invA = 1.0f / (denA + 1e-6f);
        const float invB = 1.0f / (denB + 1e-6f);
        if (it == ITERS - 1) {
#define WR(IDX, NV, EL, OFF, INV) \
            Ob[(size_t)(chbase + (IDX)) * HWp + (OFF)] = (float)NV[EL] * (INV)
            WR(0,  nA0, 0, offA, invA); WR(1,  nA0, 1, offA, invA);
            WR(2,  nA1, 0, offA, invA); WR(3,  nA1, 1, offA, invA);
            WR(4,  nA2, 0, offA, invA); WR(5,  nA2, 1, offA, invA);
            WR(6,  nA3, 0, offA, invA); WR(7,  nA3, 1, offA, invA);
            WR(8,  nA4, 0, offA, invA); WR(9,  nA4, 1, offA, invA);
            WR(10, nA5, 0, offA, invA); WR(11, nA5, 1, offA, invA);
            WR(12, nA6, 0, offA, invA); WR(13, nA6, 1, offA, invA);
            WR(14, nA7, 0, offA, invA); WR(15, nA7, 1, offA, invA);
            WR(0,  nB0, 0, offA + WW, invB); WR(1,  nB0, 1, offA + WW, invB);
            WR(2,  nB1, 0, offA + WW, invB); WR(3,  nB1, 1, offA + WW, invB);
            WR(4,  nB2, 0, offA + WW, invB); WR(5,  nB2, 1, offA + WW, invB);
            WR(6,  nB3, 0, offA + WW, invB); WR(7,  nB3, 1, offA + WW, invB);
            WR(8,  nB4, 0, offA + WW, invB); WR(9,  nB4, 1, offA + WW, invB);
            WR(10, nB5, 0, offA + WW, invB); WR(11, nB5, 1, offA + WW, invB);
            WR(12, nB6, 0, offA + WW, invB); WR(13, nB6, 1, offA + WW, invB);
            WR(14, nB7, 0, offA + WW, invB); WR(15, nB7, 1, offA + WW, invB);
#undef WR
        } else {
            // zs_new = A2 * (num * inv): fold A2 into the inverse
            const float iaA = invA * A2f;
            const float iaB = invB * A2f;
            const h2 ivA = pk2(iaA, iaA);
            const h2 ivB = pk2(iaB, iaB);
            zA0 = nA0 * ivA; zA1 = nA1 * ivA; zA2 = nA2 * ivA; zA3 = nA3 * ivA;
            zA4 = nA4 * ivA; zA5 = nA5 * ivA; zA6 = nA6 * ivA; zA7 = nA7 * ivA;
            zB0 = nB0 * ivB; zB1 = nB1 * ivB; zB2 = nB2 * ivB; zB3 = nB3 * ivB;
            zB4 = nB4 * ivB; zB5 = nB5 * ivB; zB6 = nB6 * ivB; zB7 = nB7 * ivB;
        }
    }
#undef NB
}

extern "C" void kernel_launch(void* const* d_in, const int* in_sizes, int n_in,
                              void* d_out, int out_size, void* d_ws, size_t ws_size,
                              hipStream_t stream) {
    const float* E   = (const float*)d_in[0];
    const float* lbw = (const float*)d_in[1];
    float* out       = (float*)d_out;

    const int B = in_sizes[0] / (Dch * HWp);       // = 2
    dim3 grid(WW / BW, HH / BH, B);                // (16,8,2) = 256 blocks
    dim3 block(NTHR, 1, 1);                        // 512 threads
    hipLaunchKernelGGL(meanshift_kernel, grid, block, 0, stream, E, lbw, out);
}